// Round 8
// baseline (380.594 us; speedup 1.0000x reference)
//
#include <hip/hip_runtime.h>
#include <cstdint>
#include <cstddef>

namespace {

constexpr int B_ = 1024;
constexpr int T_ = 512;
constexpr int H_ = 64;
constexpr int NG = 64;            // batch groups (16 rows each)
constexpr int D_RING = 64;        // ring depth in steps
constexpr int CP = 16;            // poll chunk (baseline-proven)
constexpr int SLOT_BYTES = 16 * 64 * 2;   // one h-tile: [16 rows][64 hd] bf16

constexpr float L2E  = 1.4426950408889634f;   // log2(e)

typedef short bf16x8 __attribute__((ext_vector_type(8)));
typedef float f32x4  __attribute__((ext_vector_type(4)));

// hardware exp2 / rcp (pure, CSE-able; ~1 ulp — far inside the 2.2e-3 budget)
__device__ __forceinline__ float exp2_hw(float x) {
    float r; asm("v_exp_f32 %0, %1" : "=v"(r) : "v"(x)); return r;
}
__device__ __forceinline__ float rcp_hw(float x) {
    float r; asm("v_rcp_f32 %0, %1" : "=v"(r) : "v"(x)); return r;
}

__device__ __forceinline__ unsigned short f2bf(float f) {   // RNE fp32 -> bf16
    unsigned u = __float_as_uint(f);
    u += 0x7FFF + ((u >> 16) & 1);
    return (unsigned short)(u >> 16);
}

// packed RNE fp32x2 -> bf16x2 (low = a, high = b)
__device__ __forceinline__ unsigned cvtpk_bf16(float a, float b) {
    unsigned r;
    asm("v_cvt_pk_bf16_f32 %0, %1, %2" : "=v"(r) : "v"(a), "v"(b));
    return r;
}

// LDS-only barrier: does NOT drain vmcnt — global ops stay in flight.
__device__ __forceinline__ void lds_barrier() {
    asm volatile("s_waitcnt lgkmcnt(0)\n\ts_barrier" ::: "memory");
}

// device-coherent (sc0 sc1) 16B store: write-through -> LLC-visible
__device__ __forceinline__ void ring_store16(void* dst, bf16x8 v) {
    asm volatile("global_store_dwordx4 %0, %1, off sc0 sc1"
                 :: "v"(dst), "v"(v) : "memory");
}
// coherent flag load (bypasses stale L2) — BLOCKING
__device__ __forceinline__ int flag_load(const int* p) {
    int v;
    asm volatile("global_load_dword %0, %1, off sc0 sc1\n\t"
                 "s_waitcnt vmcnt(0)" : "=v"(v) : "v"(p) : "memory");
    return v;
}
// release flag store WITH drain (epilogue only)
__device__ __forceinline__ void flag_store_drain(int* p, int v) {
    asm volatile("s_waitcnt vmcnt(0)\n\t"
                 "global_store_dword %0, %1, off sc0 sc1"
                 :: "v"(p), "v"(v) : "memory");
}
// plain coherent flag store (drain-free publish / consumption progress)
__device__ __forceinline__ void flag_store(int* p, int v) {
    asm volatile("global_store_dword %0, %1, off sc0 sc1"
                 :: "v"(p), "v"(v) : "memory");
}
__device__ __forceinline__ void spin_ge(const int* p, int tgt) {
    while (flag_load(p) < tgt) __builtin_amdgcn_s_sleep(1);
}

// one h-value cell update (round-5 verified reduced-trans form).
// Gates PRE-SCALED (i,f,o by L2E; g by 2*L2E):
//   si*tg = (1-B)/((1+A)(1+B)); sf = rcp(1+F);
//   h = (1-C)/((1+D)(1+C)), C-arg clamped to +-80 (c unbounded; clamped
//   tails give h = +-so exactly).
template<int R>
__device__ __forceinline__ float cell_one(const f32x4* accC, float& cr) {
    const float gi = accC[0][R], gf = accC[1][R], gg = accC[2][R], go = accC[3][R];
    const float A  = exp2_hw(-gi);
    const float F  = exp2_hw(-gf);
    const float Bx = exp2_hw(-gg);
    const float D  = exp2_hw(-go);
    const float r1 = rcp_hw((1.0f + A) * (1.0f + Bx));
    const float r2 = rcp_hw(1.0f + F);
    cr = __builtin_fmaf(cr, r2, (1.0f - Bx) * r1);
    float ca = cr * (-2.0f * L2E);
    ca = fminf(fmaxf(ca, -80.0f), 80.0f);
    const float C  = exp2_hw(ca);
    const float r3 = rcp_hw((1.0f + D) * (1.0f + C));
    return (1.0f - C) * r3;
}

// ---------------------------------------------------------------------------
// Setup kernels.  Weights/biases are PRE-SCALED (see cell_one).
// ---------------------------------------------------------------------------
__global__ void init_flags(int* p, int n) {
    int i = blockIdx.x * 256 + threadIdx.x;
    if (i < n) p[i] = -1;
}

// [256][64] fp32 -> bf16, row-dependent scale
__global__ void cvt_bf16_kernel(const float* __restrict__ src,
                                unsigned short* __restrict__ dst, int n) {
    int i = blockIdx.x * 256 + threadIdx.x;
    if (i < n) {
        int row = i >> 6;                       // gate row 0..255
        float sc = ((row >> 6) == 2) ? 2.0f * L2E : L2E;
        dst[i] = f2bf(src[i] * sc);
    }
}

// wih0: [256][6] fp32 -> [256][8] bf16 (k=6,7 zero), scaled
__global__ void cvt_wih0_kernel(const float* __restrict__ src,
                                unsigned short* __restrict__ dst) {
    int i = blockIdx.x * 256 + threadIdx.x;   // 2048
    int g = i >> 3, k = i & 7;
    float sc = ((g >> 6) == 2) ? 2.0f * L2E : L2E;
    dst[i] = (k < 6) ? f2bf(src[g * 6 + k] * sc) : (unsigned short)0;
}

// xPk[t][g][r16][k8] bf16: L0's A-frag-ready x (k 0..5 valid, 6,7 zero)
__global__ void build_xpk(const float* __restrict__ x,
                          unsigned short* __restrict__ xPk) {
    int idx = blockIdx.x * 256 + threadIdx.x;   // T*NG*16*8 = 4.19M
    int k = idx & 7, r = (idx >> 3) & 15, g = (idx >> 7) & 63, t = idx >> 13;
    float v = (k < 6) ? x[((size_t)(g * 16 + r) * T_ + t) * 6 + k] : 0.f;
    xPk[idx] = f2bf(v);
}

// ---------------------------------------------------------------------------
// Pipelined LSTM body (round-5 PASS structure, 4 waves, 256 threads).
// CHANGE THIS ROUND — drain-free per-step publish:
//  At step t, after W0's counted wait, everything except the youngest
//  2 (LAY0) / 7 (LAY1) vmem ops has retired — in particular ring stores of
//  h(t-3) (LAY0) / h(t-4) (LAY1). tid 0 publishes that value with a PLAIN
//  store EVERY step; the old cadence-16 drained publish is deleted.
//  Queue-count adjustment: the publish store (Sf) rides W0's queue; LAY1
//  W0's wait becomes vmcnt(7) (Sf+R,R+S,S @t-1 + S,S@t-2 = 7 younger than
//  the needed R,R@t-2). LAY0 W0 stays vmcnt(2) (Sf older than the needed R).
//  Safety cushion: consumer gate asks prog >= s+15, so a slot is never read
//  until the producer is >=18 steps past storing it (~11us >> LLC store
//  latency) — publish-value precision is absorbed by gate hysteresis.
//  Gates / backpressure / cons publishes / ramp / tail: byte-identical to
//  the round-5 PASS kernel.
//
// Wait counts (in-order vmem retirement; loads issued before stores):
//  LAY0: W0 [Sf,R,S,S]/step -> vmcnt(2); others [R]/step -> vmcnt(0)
//  LAY1: W0 [Sf,R,R,S,S]/step -> vmcnt(7) (depth-3); others [R,R] -> vmcnt(2)
//  LAY2: [R,R]/step -> vmcnt(2)     (no publish; consumer only)
//  Tail 4 steps peeled with vmcnt(0).
// ---------------------------------------------------------------------------
template<int LAY>
__device__ __forceinline__ void pipe_body(
    int g,
    const unsigned short* __restrict__ xPk,
    const unsigned short* __restrict__ wih,
    const unsigned short* __restrict__ whh,
    const float* __restrict__ bih, const float* __restrict__ bhh,
    const unsigned short* __restrict__ ringIn, unsigned short* __restrict__ ringOut,
    const int* progIn, int* progOut, int* consInP, const int* consOutP,
    float* __restrict__ hlast, unsigned short* lds)
{
    const int tid = threadIdx.x;
    const int l   = tid & 63;
    const int w   = tid >> 6;
    const int r16 = l & 15;
    const int kq  = l >> 4;
    const int hdim = w * 16 + r16;

    // ---- weight fragments (B-frag: col=l&15 -> gate row, k=8*kq+i) ----
    bf16x8 whh_f[4][2], wih_f[4][2];
    f32x4  bias_acc[4];
    #pragma unroll
    for (int d = 0; d < 4; ++d) {
        const int gg = d * 64 + hdim;
        const float sc = (d == 2) ? 2.0f * L2E : L2E;
        const float b = (bih[gg] + bhh[gg]) * sc;
        bias_acc[d] = f32x4{b, b, b, b};
        whh_f[d][0] = *(const bf16x8*)(whh + gg * 64 + kq * 8);
        whh_f[d][1] = *(const bf16x8*)(whh + gg * 64 + 32 + kq * 8);
        if constexpr (LAY == 0) {
            bf16x8 z = {};
            wih_f[d][0] = (kq == 0) ? *(const bf16x8*)(wih + gg * 8) : z;
            wih_f[d][1] = z;
        } else {
            wih_f[d][0] = *(const bf16x8*)(wih + gg * 64 + kq * 8);
            wih_f[d][1] = *(const bf16x8*)(wih + gg * 64 + 32 + kq * 8);
        }
    }

    // ---- LDS addressing (XOR swizzle, verified r4-r9) ----
    char* ldsb = (char*)lds;
    const int rdA0 = r16 * 128 + (((0 + kq) ^ (r16 & 7)) << 4);
    const int rdA1 = r16 * 128 + (((4 + kq) ^ (r16 & 7)) << 4);
    int wrA[4];
    #pragma unroll
    for (int r = 0; r < 4; ++r) {
        const int row = 4 * kq + r;
        wrA[r] = row * 128 + (((hdim >> 3) ^ (row & 7)) << 4) + (hdim & 7) * 2;
    }
    // ring lane offsets (linear row-major inside a slot)
    const int rOffA = r16 * 128 + kq * 16;
    const int rOffB = r16 * 128 + 64 + kq * 16;

    // L0 xPk row address (wave-wide; lanes sharing r16 read the same 16B)
    auto xrow = [&](int t) -> const char* {
        return (const char*)xPk + (((size_t)t * NG + g) * 16 + r16) * 16;
    };

    // ---- zero LDS (h[-1]=0), init cell state ----
    ((uint4*)ldsb)[tid] = make_uint4(0, 0, 0, 0);   // 256*16B = 4 KiB
    float c[4] = {0.f, 0.f, 0.f, 0.f};
    lds_barrier();

    // ---- ramp ----
    bf16x8 cur0 = {};                       // LAY0 x register
    bf16x8 curA0 = {}, curA1 = {};          // LAY>0 parity-0 x regs
    bf16x8 curB0 = {}, curB1 = {};          // LAY>0 parity-1 x regs
    f32x4 accA[4], accB[4];
    {
        bf16x8 x0a = {}, x0b = {};
        if constexpr (LAY > 0) {
            spin_ge(progIn, (CP - 1 < T_ - 1) ? CP - 1 : T_ - 1);
            const char* s0 = (const char*)ringIn;                     // slot 0
            const char* s1 = (const char*)ringIn + SLOT_BYTES;        // slot 1
            const char* s2 = (const char*)ringIn + 2 * SLOT_BYTES;    // slot 2
            asm volatile(
                "global_load_dwordx4 %0, %6, off sc0 sc1\n\t"
                "global_load_dwordx4 %1, %7, off sc0 sc1\n\t"
                "global_load_dwordx4 %2, %8, off sc0 sc1\n\t"
                "global_load_dwordx4 %3, %9, off sc0 sc1\n\t"
                "global_load_dwordx4 %4, %10, off sc0 sc1\n\t"
                "global_load_dwordx4 %5, %11, off sc0 sc1\n\t"
                "s_waitcnt vmcnt(0)"
                : "=v"(x0a), "=v"(x0b), "=v"(curA0), "=v"(curA1),
                  "=v"(curB0), "=v"(curB1)
                : "v"(s0 + rOffA), "v"(s0 + rOffB),
                  "v"(s1 + rOffA), "v"(s1 + rOffB),
                  "v"(s2 + rOffA), "v"(s2 + rOffB)
                : "memory");
            __builtin_amdgcn_sched_barrier(0);
        } else {
            asm volatile(
                "global_load_dwordx4 %0, %2, off\n\t"
                "global_load_dwordx4 %1, %3, off\n\t"
                "s_waitcnt vmcnt(0)"
                : "=v"(x0a), "=v"(cur0)
                : "v"(xrow(0)), "v"(xrow(1))
                : "memory");
            __builtin_amdgcn_sched_barrier(0);
        }
        #pragma unroll
        for (int d = 0; d < 4; ++d) {
            accA[d] = __builtin_amdgcn_mfma_f32_16x16x32_bf16(x0a, wih_f[d][0], bias_acc[d], 0, 0, 0);
            if constexpr (LAY != 0)
                accA[d] = __builtin_amdgcn_mfma_f32_16x16x32_bf16(x0b, wih_f[d][1], accA[d], 0, 0, 0);
        }
    }

    // ---- one step ----
    auto step = [&](int t, int par, bool tail, f32x4* accC, f32x4* accN,
                    bf16x8& cp0, bf16x8& cp1) {
        // producer backpressure (chunk edge; w0 only — the sole ring-storer)
        if constexpr (LAY < 2) {
            if (w == 0 && (t & (CP - 1)) == 0) spin_ge(consOutP, t + CP - D_RING);
        }

        // h[t-1] A-frags from LDS
        const bf16x8 ha = *(const bf16x8*)(ldsb + ((par ^ 1) << 11) + rdA0);
        const bf16x8 hb = *(const bf16x8*)(ldsb + ((par ^ 1) << 11) + rdA1);

        // h-part MFMAs (critical chain)
        #pragma unroll
        for (int d = 0; d < 4; ++d) {
            accC[d] = __builtin_amdgcn_mfma_f32_16x16x32_bf16(ha, whh_f[d][0], accC[d], 0, 0, 0);
            accC[d] = __builtin_amdgcn_mfma_f32_16x16x32_bf16(hb, whh_f[d][1], accC[d], 0, 0, 0);
        }

        // wait for x(t+1) regs (counts in header; publish store included)
        if (tail) {
            asm volatile("s_waitcnt vmcnt(0)" ::: "memory");
        } else if constexpr (LAY == 0) {
            if (w == 0) asm volatile("s_waitcnt vmcnt(2)" ::: "memory");
            else        asm volatile("s_waitcnt vmcnt(0)" ::: "memory");
        } else if constexpr (LAY == 1) {
            if (w == 0) asm volatile("s_waitcnt vmcnt(7)" ::: "memory");
            else        asm volatile("s_waitcnt vmcnt(2)" ::: "memory");
        } else {
            asm volatile("s_waitcnt vmcnt(2)" ::: "memory");
        }
        __builtin_amdgcn_sched_barrier(0);

        // DRAIN-FREE per-step publish: after the counted wait, ring stores
        // of h(t-3) (LAY0) / h(t-4) (LAY1) have retired (all but the
        // youngest 2/7 ops). Values strictly increase; early negatives are
        // below every consumer target -> harmless.
        if constexpr (LAY == 0) {
            if (tid == 0) flag_store(progOut, t - 3);
        } else if constexpr (LAY == 1) {
            if (tid == 0) flag_store(progOut, t - 4);
        }

        // x-part of t+1 into accN (off-chain; overlaps cell update)
        if (t + 1 < T_) {
            if constexpr (LAY == 0) {
                #pragma unroll
                for (int d = 0; d < 4; ++d)
                    accN[d] = __builtin_amdgcn_mfma_f32_16x16x32_bf16(cur0, wih_f[d][0], bias_acc[d], 0, 0, 0);
            } else {
                #pragma unroll
                for (int d = 0; d < 4; ++d) {
                    accN[d] = __builtin_amdgcn_mfma_f32_16x16x32_bf16(cp0, wih_f[d][0], bias_acc[d], 0, 0, 0);
                    accN[d] = __builtin_amdgcn_mfma_f32_16x16x32_bf16(cp1, wih_f[d][1], accN[d], 0, 0, 0);
                }
            }
        }

        // issue x loads FIRST (keeps them older than this step's stores)
        {
            const int s = (LAY > 0) ? t + 3 : t + 2;
            if (s < T_) {
                if constexpr (LAY > 0) {
                    if ((s & (CP - 1)) == 0) {
                        int tgt = s + CP - 1; if (tgt > T_ - 1) tgt = T_ - 1;
                        spin_ge(progIn, tgt);
                    }
                    const char* src = (const char*)ringIn + (s & (D_RING - 1)) * SLOT_BYTES;
                    asm volatile(
                        "global_load_dwordx4 %0, %2, off sc0 sc1\n\t"
                        "global_load_dwordx4 %1, %3, off sc0 sc1"
                        : "=v"(cp0), "=v"(cp1)
                        : "v"(src + rOffA), "v"(src + rOffB)
                        : "memory");
                } else {
                    asm volatile("global_load_dwordx4 %0, %1, off"
                                 : "=v"(cur0) : "v"(xrow(s)) : "memory");
                }
            }
        }

        // ring store of h[t-1] (wave 0; values live in ha/hb). Runs at t=0
        // too (slot 63 dummy; overwritten a revolution before any read).
        if constexpr (LAY < 2) {
            if (w == 0) {
                char* dst = (char*)ringOut + ((t - 1) & (D_RING - 1)) * SLOT_BYTES;
                ring_store16(dst + rOffA, ha);
                ring_store16(dst + rOffB, hb);
            }
        }

        // cell update (lane-local: rows 4kq+r at column hdim)
        float h[4];
        h[0] = cell_one<0>(accC, c[0]);
        h[1] = cell_one<1>(accC, c[1]);
        h[2] = cell_one<2>(accC, c[2]);
        h[3] = cell_one<3>(accC, c[3]);
        const unsigned p01 = cvtpk_bf16(h[0], h[1]);
        const unsigned p23 = cvtpk_bf16(h[2], h[3]);
        char* wbase = ldsb + (par << 11);
        *(unsigned short*)(wbase + wrA[0]) = (unsigned short)(p01 & 0xffff);
        *(unsigned short*)(wbase + wrA[1]) = (unsigned short)(p01 >> 16);
        *(unsigned short*)(wbase + wrA[2]) = (unsigned short)(p23 & 0xffff);
        *(unsigned short*)(wbase + wrA[3]) = (unsigned short)(p23 >> 16);
        if constexpr (LAY == 2) {
            if (t == T_ - 1) {
                #pragma unroll
                for (int r = 0; r < 4; ++r)
                    hlast[(g * 16 + kq * 4 + r) * 64 + hdim] = h[r];
            }
        }

        lds_barrier();   // h[t] visible; global ops stay in flight

        // consumption progress publish (plain store; baseline-identical)
        if constexpr (LAY > 0) {
            if (tid == 0 && (t & (CP - 1)) == CP - 1) flag_store(consInP, t);
        }
    };

    #pragma unroll 1
    for (int t = 0; t < T_ - 4; t += 2) {
        step(t,     0, false, accA, accB, curA0, curA1);
        step(t + 1, 1, false, accB, accA, curB0, curB1);
    }
    // tail: last 4 steps with full drains (load issue has stopped; counted
    // waits would under-wait)
    step(T_ - 4, 0, true, accA, accB, curA0, curA1);
    step(T_ - 3, 1, true, accB, accA, curB0, curB1);
    step(T_ - 2, 0, true, accA, accB, curA0, curA1);
    step(T_ - 1, 1, true, accB, accA, curB0, curB1);

    // ---- epilogue: publish h[T-1] + tail chunk (drained release) ----
    if constexpr (LAY < 2) {
        if (w == 0) {
            const int par = (T_ - 1) & 1;
            const bf16x8 ha = *(const bf16x8*)(ldsb + (par << 11) + rdA0);
            const bf16x8 hb = *(const bf16x8*)(ldsb + (par << 11) + rdA1);
            char* dst = (char*)ringOut + ((T_ - 1) & (D_RING - 1)) * SLOT_BYTES;
            ring_store16(dst + rOffA, ha);
            ring_store16(dst + rOffB, hb);
        }
        lds_barrier();
        if (tid == 0) flag_store_drain(progOut, T_ - 1);
    }
}

__global__ __launch_bounds__(256, 1)
void lstm_pipe(const unsigned short* __restrict__ xPk,
               const unsigned short* __restrict__ wih0p,
               const unsigned short* __restrict__ wih1,
               const unsigned short* __restrict__ wih2,
               const unsigned short* __restrict__ whh0,
               const unsigned short* __restrict__ whh1,
               const unsigned short* __restrict__ whh2,
               const float* __restrict__ bih0, const float* __restrict__ bhh0,
               const float* __restrict__ bih1, const float* __restrict__ bhh1,
               const float* __restrict__ bih2, const float* __restrict__ bhh2,
               unsigned short* __restrict__ ring, int* __restrict__ flags,
               float* __restrict__ hlast)
{
    __shared__ unsigned short lds[2][1024];   // 4 KiB double-buffered h tile

    const int g   = blockIdx.x & 63;
    const int lay = blockIdx.x >> 6;

    const size_t GSHORTS = (size_t)D_RING * SLOT_BYTES / 2;     // per (iface,g)
    unsigned short* r0 = ring + ((size_t)0 * NG + g) * GSHORTS;
    unsigned short* r1 = ring + ((size_t)1 * NG + g) * GSHORTS;
    int* prog0 = flags + (0 * 64 + g) * 16;
    int* prog1 = flags + (1 * 64 + g) * 16;
    int* cons0 = flags + (128 + 0 * 64 + g) * 16;
    int* cons1 = flags + (128 + 1 * 64 + g) * 16;

    if (lay == 0) {
        pipe_body<0>(g, xPk, wih0p, whh0, bih0, bhh0,
                     nullptr, r0, nullptr, prog0, nullptr, cons0,
                     hlast, &lds[0][0]);
    } else if (lay == 1) {
        pipe_body<1>(g, xPk, wih1, whh1, bih1, bhh1,
                     r0, r1, prog0, prog1, cons0, cons1,
                     hlast, &lds[0][0]);
    } else {
        pipe_body<2>(g, xPk, wih2, whh2, bih2, bhh2,
                     r1, nullptr, prog1, nullptr, cons1, nullptr,
                     hlast, &lds[0][0]);
    }
}

// ---------------------------------------------------------------------------
// MLP head: one block per batch row. 64 -> 128 relu -> 64 relu -> 2.
// ---------------------------------------------------------------------------
__global__ __launch_bounds__(128)
void mlp_head_kernel(const float* __restrict__ hlast,
                     const float* __restrict__ fc1_w, const float* __restrict__ fc1_b,
                     const float* __restrict__ fc3_w, const float* __restrict__ fc3_b,
                     const float* __restrict__ fc2_w, const float* __restrict__ fc2_b,
                     float* __restrict__ outp)
{
    __shared__ float s_h[H_];
    __shared__ float s_z1[128];
    __shared__ float s_z3[64];
    const int b = blockIdx.x, tid = threadIdx.x;

    if (tid < H_) s_h[tid] = hlast[b * H_ + tid];
    __syncthreads();

    {
        float acc = fc1_b[tid];
        #pragma unroll
        for (int k = 0; k < H_; ++k) acc += fc1_w[tid * H_ + k] * s_h[k];
        s_z1[tid] = fmaxf(acc, 0.0f);
    }
    __syncthreads();

    if (tid < 64) {
        float acc = fc3_b[tid];
        #pragma unroll
        for (int k = 0; k < 128; ++k) acc += fc3_w[tid * 128 + k] * s_z1[k];
        s_z3[tid] = fmaxf(acc, 0.0f);
    }
    __syncthreads();

    if (tid < 2) {
        float acc = fc2_b[tid];
        #pragma unroll
        for (int k = 0; k < 64; ++k) acc += fc2_w[tid * 64 + k] * s_z3[k];
        outp[b * 2 + tid] = acc;
    }
}

} // namespace

extern "C" void kernel_launch(void* const* d_in, const int* in_sizes, int n_in,
                              void* d_out, int out_size, void* d_ws, size_t ws_size,
                              hipStream_t stream) {
    (void)in_sizes; (void)n_in; (void)out_size; (void)ws_size;

    const float* x     = (const float*)d_in[0];
    const float* wih0  = (const float*)d_in[1];
    const float* whh0  = (const float*)d_in[2];
    const float* bih0  = (const float*)d_in[3];
    const float* bhh0  = (const float*)d_in[4];
    const float* wih1  = (const float*)d_in[5];
    const float* whh1  = (const float*)d_in[6];
    const float* bih1  = (const float*)d_in[7];
    const float* bhh1  = (const float*)d_in[8];
    const float* wih2  = (const float*)d_in[9];
    const float* whh2  = (const float*)d_in[10];
    const float* bih2  = (const float*)d_in[11];
    const float* bhh2  = (const float*)d_in[12];
    const float* fc1_w = (const float*)d_in[13];
    const float* fc1_b = (const float*)d_in[14];
    const float* fc3_w = (const float*)d_in[15];
    const float* fc3_b = (const float*)d_in[16];
    const float* fc2_w = (const float*)d_in[17];
    const float* fc2_b = (const float*)d_in[18];
    float* out = (float*)d_out;

    // ---- workspace layout ----
    char* base = (char*)d_ws;
    const size_t RING_B = (size_t)2 * NG * D_RING * SLOT_BYTES;      // 16 MiB
    const size_t XPK_B  = (size_t)T_ * NG * 16 * 8 * 2;              // 8 MiB
    const size_t FLAG_B = 4096 * sizeof(int);                        // 16 KiB
    unsigned short* ring  = (unsigned short*)(base);
    unsigned short* xPk   = (unsigned short*)(base + RING_B);
    int*            flags = (int*)(base + RING_B + XPK_B);
    float*          hlast = (float*)(base + RING_B + XPK_B + FLAG_B);
    char* wp = base + RING_B + XPK_B + FLAG_B + (size_t)B_ * H_ * 4;
    unsigned short* whh_b[3];
    for (int i = 0; i < 3; ++i) { whh_b[i] = (unsigned short*)wp; wp += 256 * 64 * 2; }
    unsigned short* wih_b1 = (unsigned short*)wp; wp += 256 * 64 * 2;
    unsigned short* wih_b2 = (unsigned short*)wp; wp += 256 * 64 * 2;
    unsigned short* wih0p  = (unsigned short*)wp; wp += 256 * 8 * 2;

    // ---- setup: flags, weights (pre-scaled), packed x ----
    init_flags<<<16, 256, 0, stream>>>(flags, 4096);
    const int NW = 256 * 64;
    cvt_bf16_kernel<<<NW / 256, 256, 0, stream>>>(whh0, whh_b[0], NW);
    cvt_bf16_kernel<<<NW / 256, 256, 0, stream>>>(whh1, whh_b[1], NW);
    cvt_bf16_kernel<<<NW / 256, 256, 0, stream>>>(whh2, whh_b[2], NW);
    cvt_bf16_kernel<<<NW / 256, 256, 0, stream>>>(wih1, wih_b1, NW);
    cvt_bf16_kernel<<<NW / 256, 256, 0, stream>>>(wih2, wih_b2, NW);
    cvt_wih0_kernel<<<8, 256, 0, stream>>>(wih0, wih0p);
    build_xpk<<<(T_ * NG * 16 * 8) / 256, 256, 0, stream>>>(x, xPk);

    // ---- pipelined LSTM stack: 192 blocks (64 groups x 3 layers) ----
    lstm_pipe<<<192, 256, 0, stream>>>(xPk, wih0p, wih_b1, wih_b2,
                                       whh_b[0], whh_b[1], whh_b[2],
                                       bih0, bhh0, bih1, bhh1, bih2, bhh2,
                                       ring, flags, hlast);

    // ---- MLP head ----
    mlp_head_kernel<<<B_, 128, 0, stream>>>(hlast, fc1_w, fc1_b, fc3_w, fc3_b,
                                            fc2_w, fc2_b, out);
}

// Round 9
// 366.826 us; speedup vs baseline: 1.0375x; 1.0375x over previous
//
#include <hip/hip_runtime.h>
#include <cstdint>
#include <cstddef>

namespace {

constexpr int B_ = 1024;
constexpr int T_ = 512;
constexpr int H_ = 64;
constexpr int NG = 64;            // batch groups (16 rows each)
constexpr int D_RING = 64;        // ring depth in steps
constexpr int CP = 16;            // poll/publish chunk (baseline-proven)
constexpr int SLOT_BYTES = 16 * 64 * 2;   // one h-tile: [16 rows][64 hd] bf16

constexpr float L2E  = 1.4426950408889634f;   // log2(e)

typedef short bf16x8 __attribute__((ext_vector_type(8)));
typedef float f32x4  __attribute__((ext_vector_type(4)));
typedef float f32x2  __attribute__((ext_vector_type(2)));

// hardware exp2 / rcp (pure, CSE-able; ~1 ulp — far inside the 2.2e-3 budget)
__device__ __forceinline__ float exp2_hw(float x) {
    float r; asm("v_exp_f32 %0, %1" : "=v"(r) : "v"(x)); return r;
}
__device__ __forceinline__ float rcp_hw(float x) {
    float r; asm("v_rcp_f32 %0, %1" : "=v"(r) : "v"(x)); return r;
}

__device__ __forceinline__ unsigned short f2bf(float f) {   // RNE fp32 -> bf16
    unsigned u = __float_as_uint(f);
    u += 0x7FFF + ((u >> 16) & 1);
    return (unsigned short)(u >> 16);
}

// packed RNE fp32x2 -> bf16x2 (low = a, high = b)
__device__ __forceinline__ unsigned cvtpk_bf16(float a, float b) {
    unsigned r;
    asm("v_cvt_pk_bf16_f32 %0, %1, %2" : "=v"(r) : "v"(a), "v"(b));
    return r;
}

// 6 fp32 -> L0 A-frag bf16x8 (k=0..5 valid, 6,7 zero) — same f2bf as the
// old build_xpk kernel: bit-identical bf16 values.
__device__ __forceinline__ bf16x8 cvt_x6(f32x2 a, f32x2 b, f32x2 c) {
    bf16x8 r = {};
    r[0] = (short)f2bf(a[0]); r[1] = (short)f2bf(a[1]);
    r[2] = (short)f2bf(b[0]); r[3] = (short)f2bf(b[1]);
    r[4] = (short)f2bf(c[0]); r[5] = (short)f2bf(c[1]);
    return r;
}

// LDS-only barrier: does NOT drain vmcnt — global ops stay in flight.
__device__ __forceinline__ void lds_barrier() {
    asm volatile("s_waitcnt lgkmcnt(0)\n\ts_barrier" ::: "memory");
}

// device-coherent (sc0 sc1) 16B store: write-through -> LLC-visible
__device__ __forceinline__ void ring_store16(void* dst, bf16x8 v) {
    asm volatile("global_store_dwordx4 %0, %1, off sc0 sc1"
                 :: "v"(dst), "v"(v) : "memory");
}
// coherent flag load (bypasses stale L2) — BLOCKING
__device__ __forceinline__ int flag_load(const int* p) {
    int v;
    asm volatile("global_load_dword %0, %1, off sc0 sc1\n\t"
                 "s_waitcnt vmcnt(0)" : "=v"(v) : "v"(p) : "memory");
    return v;
}
// release flag store: drain own stores, then coherent store (producers only)
__device__ __forceinline__ void flag_store_drain(int* p, int v) {
    asm volatile("s_waitcnt vmcnt(0)\n\t"
                 "global_store_dword %0, %1, off sc0 sc1"
                 :: "v"(p), "v"(v) : "memory");
}
// plain coherent flag store (consumption progress: no drain needed)
__device__ __forceinline__ void flag_store(int* p, int v) {
    asm volatile("global_store_dword %0, %1, off sc0 sc1"
                 :: "v"(p), "v"(v) : "memory");
}
__device__ __forceinline__ void spin_ge(const int* p, int tgt) {
    while (flag_load(p) < tgt) __builtin_amdgcn_s_sleep(1);
}

// one h-value cell update (round-5 verified reduced-trans form).
// Gates PRE-SCALED (i,f,o by L2E; g by 2*L2E):
//   si*tg = (1-B)/((1+A)(1+B)); sf = rcp(1+F);
//   h = (1-C)/((1+D)(1+C)), C-arg clamped to +-80 (c unbounded; clamped
//   tails give h = +-so exactly).
template<int R>
__device__ __forceinline__ float cell_one(const f32x4* accC, float& cr) {
    const float gi = accC[0][R], gf = accC[1][R], gg = accC[2][R], go = accC[3][R];
    const float A  = exp2_hw(-gi);
    const float F  = exp2_hw(-gf);
    const float Bx = exp2_hw(-gg);
    const float D  = exp2_hw(-go);
    const float r1 = rcp_hw((1.0f + A) * (1.0f + Bx));
    const float r2 = rcp_hw(1.0f + F);
    cr = __builtin_fmaf(cr, r2, (1.0f - Bx) * r1);
    float ca = cr * (-2.0f * L2E);
    ca = fminf(fmaxf(ca, -80.0f), 80.0f);
    const float C  = exp2_hw(ca);
    const float r3 = rcp_hw((1.0f + D) * (1.0f + C));
    return (1.0f - C) * r3;
}

// ---------------------------------------------------------------------------
// SINGLE fused setup kernel (replaces init_flags + 5x cvt + wih0p = 7
// launches). Weights/biases PRE-SCALED: gate rows i,f,o by log2(e), g rows
// (block 2) by 2*log2(e).
//   i <  81920 : five [256][64] weight cvts (which = i>>14)
//   i <  83968 : wih0p [256][8] (k=6,7 zero)
//   i <  88064 : flags = -1
// ---------------------------------------------------------------------------
__global__ void setup_all(const float* __restrict__ whh0,
                          const float* __restrict__ whh1,
                          const float* __restrict__ whh2,
                          const float* __restrict__ wih1,
                          const float* __restrict__ wih2,
                          const float* __restrict__ wih0,
                          unsigned short* __restrict__ whhb0,
                          unsigned short* __restrict__ whhb1,
                          unsigned short* __restrict__ whhb2,
                          unsigned short* __restrict__ wihb1,
                          unsigned short* __restrict__ wihb2,
                          unsigned short* __restrict__ wih0p,
                          int* __restrict__ flags)
{
    const int i = blockIdx.x * 256 + threadIdx.x;
    if (i < 81920) {
        const int which = i >> 14;           // 0..4
        const int rem   = i & 16383;
        const float* src = (which == 0) ? whh0 : (which == 1) ? whh1 :
                           (which == 2) ? whh2 : (which == 3) ? wih1 : wih2;
        unsigned short* dst = (which == 0) ? whhb0 : (which == 1) ? whhb1 :
                              (which == 2) ? whhb2 : (which == 3) ? wihb1 : wihb2;
        const int row = rem >> 6;            // gate row 0..255
        const float sc = ((row >> 6) == 2) ? 2.0f * L2E : L2E;
        dst[rem] = f2bf(src[rem] * sc);
    } else if (i < 83968) {
        const int j = i - 81920;             // 0..2047
        const int gte = j >> 3, k = j & 7;
        const float sc = ((gte >> 6) == 2) ? 2.0f * L2E : L2E;
        wih0p[j] = (k < 6) ? f2bf(wih0[gte * 6 + k] * sc) : (unsigned short)0;
    } else if (i < 88064) {
        flags[i - 83968] = -1;
    }
}

// ---------------------------------------------------------------------------
// Pipelined LSTM body — round-5 PASS structure and flag protocol EXACTLY
// (cadence-16 drained publish, w0-only backpressure, chunk consumer spins,
// depth-3 LAY>0 prefetch). ONLY change: L0 loads x DIRECTLY as fp32
// (3x global_load_dwordx2, offsets multiples of 24 from a 256B-aligned
// base -> 8B aligned) and converts in-registers with the same f2bf as the
// deleted build_xpk -> bit-identical bf16 values. Conversion is off-chain
// on the lightest layer.
//
// Wait counts (in-order vmem retirement; loads issued before stores):
//  LAY0: W0 [R,R,R,S,S]/step -> vmcnt(2); others [R,R,R]/step -> vmcnt(0)
//  LAY1: W0 [R,R,S,S]/step -> vmcnt(6) (depth-3); others [R,R] -> vmcnt(2)
//  LAY2: [R,R]/step -> vmcnt(2)
//  Tail 4 steps peeled with vmcnt(0). Chunk-edge publish drains all.
// ---------------------------------------------------------------------------
template<int LAY>
__device__ __forceinline__ void pipe_body(
    int g,
    const float* __restrict__ xraw,
    const unsigned short* __restrict__ wih,
    const unsigned short* __restrict__ whh,
    const float* __restrict__ bih, const float* __restrict__ bhh,
    const unsigned short* __restrict__ ringIn, unsigned short* __restrict__ ringOut,
    const int* progIn, int* progOut, int* consInP, const int* consOutP,
    float* __restrict__ hlast, unsigned short* lds)
{
    const int tid = threadIdx.x;
    const int l   = tid & 63;
    const int w   = tid >> 6;
    const int r16 = l & 15;
    const int kq  = l >> 4;
    const int hdim = w * 16 + r16;

    // ---- weight fragments (B-frag: col=l&15 -> gate row, k=8*kq+i) ----
    bf16x8 whh_f[4][2], wih_f[4][2];
    f32x4  bias_acc[4];
    #pragma unroll
    for (int d = 0; d < 4; ++d) {
        const int gg = d * 64 + hdim;
        const float sc = (d == 2) ? 2.0f * L2E : L2E;
        const float b = (bih[gg] + bhh[gg]) * sc;
        bias_acc[d] = f32x4{b, b, b, b};
        whh_f[d][0] = *(const bf16x8*)(whh + gg * 64 + kq * 8);
        whh_f[d][1] = *(const bf16x8*)(whh + gg * 64 + 32 + kq * 8);
        if constexpr (LAY == 0) {
            bf16x8 z = {};
            wih_f[d][0] = (kq == 0) ? *(const bf16x8*)(wih + gg * 8) : z;
            wih_f[d][1] = z;
        } else {
            wih_f[d][0] = *(const bf16x8*)(wih + gg * 64 + kq * 8);
            wih_f[d][1] = *(const bf16x8*)(wih + gg * 64 + 32 + kq * 8);
        }
    }

    // ---- LDS addressing (XOR swizzle, verified r4-r9) ----
    char* ldsb = (char*)lds;
    const int rdA0 = r16 * 128 + (((0 + kq) ^ (r16 & 7)) << 4);
    const int rdA1 = r16 * 128 + (((4 + kq) ^ (r16 & 7)) << 4);
    int wrA[4];
    #pragma unroll
    for (int r = 0; r < 4; ++r) {
        const int row = 4 * kq + r;
        wrA[r] = row * 128 + (((hdim >> 3) ^ (row & 7)) << 4) + (hdim & 7) * 2;
    }
    // ring lane offsets (linear row-major inside a slot)
    const int rOffA = r16 * 128 + kq * 16;
    const int rOffB = r16 * 128 + 64 + kq * 16;

    // L0 raw-x row address: row b = g*16 + r16, 6 fp32 per (b,t), 24 B
    // stride in t -> sequential streaming per row. Offsets are multiples
    // of 8 (24 = 3*8) from the 256B-aligned input -> dwordx2-safe.
    auto xaddr = [&](int t) -> const char* {
        return (const char*)xraw + ((size_t)(g * 16 + r16) * T_ + t) * 24;
    };

    // ---- zero LDS (h[-1]=0), init cell state ----
    ((uint4*)ldsb)[tid] = make_uint4(0, 0, 0, 0);   // 256*16B = 4 KiB
    float c[4] = {0.f, 0.f, 0.f, 0.f};
    lds_barrier();

    // ---- ramp ----
    f32x2  xf0 = {}, xf1 = {}, xf2 = {};    // L0 in-flight fp32 x regs
    bf16x8 curA0 = {}, curA1 = {};          // LAY>0 parity-0 x regs
    bf16x8 curB0 = {}, curB1 = {};          // LAY>0 parity-1 x regs
    f32x4 accA[4], accB[4];
    {
        bf16x8 x0a = {}, x0b = {};
        if constexpr (LAY > 0) {
            spin_ge(progIn, (CP - 1 < T_ - 1) ? CP - 1 : T_ - 1);
            const char* s0 = (const char*)ringIn;                     // slot 0
            const char* s1 = (const char*)ringIn + SLOT_BYTES;        // slot 1
            const char* s2 = (const char*)ringIn + 2 * SLOT_BYTES;    // slot 2
            asm volatile(
                "global_load_dwordx4 %0, %6, off sc0 sc1\n\t"
                "global_load_dwordx4 %1, %7, off sc0 sc1\n\t"
                "global_load_dwordx4 %2, %8, off sc0 sc1\n\t"
                "global_load_dwordx4 %3, %9, off sc0 sc1\n\t"
                "global_load_dwordx4 %4, %10, off sc0 sc1\n\t"
                "global_load_dwordx4 %5, %11, off sc0 sc1\n\t"
                "s_waitcnt vmcnt(0)"
                : "=v"(x0a), "=v"(x0b), "=v"(curA0), "=v"(curA1),
                  "=v"(curB0), "=v"(curB1)
                : "v"(s0 + rOffA), "v"(s0 + rOffB),
                  "v"(s1 + rOffA), "v"(s1 + rOffB),
                  "v"(s2 + rOffA), "v"(s2 + rOffB)
                : "memory");
            __builtin_amdgcn_sched_barrier(0);
        } else {
            f32x2 a0 = {}, a1 = {}, a2 = {};
            asm volatile(
                "global_load_dwordx2 %0, %6, off\n\t"
                "global_load_dwordx2 %1, %7, off\n\t"
                "global_load_dwordx2 %2, %8, off\n\t"
                "global_load_dwordx2 %3, %9, off\n\t"
                "global_load_dwordx2 %4, %10, off\n\t"
                "global_load_dwordx2 %5, %11, off\n\t"
                "s_waitcnt vmcnt(0)"
                : "=v"(a0), "=v"(a1), "=v"(a2),
                  "=v"(xf0), "=v"(xf1), "=v"(xf2)
                : "v"(xaddr(0)), "v"(xaddr(0) + 8), "v"(xaddr(0) + 16),
                  "v"(xaddr(1)), "v"(xaddr(1) + 8), "v"(xaddr(1) + 16)
                : "memory");
            __builtin_amdgcn_sched_barrier(0);
            x0a = cvt_x6(a0, a1, a2);
        }
        #pragma unroll
        for (int d = 0; d < 4; ++d) {
            accA[d] = __builtin_amdgcn_mfma_f32_16x16x32_bf16(x0a, wih_f[d][0], bias_acc[d], 0, 0, 0);
            if constexpr (LAY != 0)
                accA[d] = __builtin_amdgcn_mfma_f32_16x16x32_bf16(x0b, wih_f[d][1], accA[d], 0, 0, 0);
        }
    }

    // ---- one step ----
    auto step = [&](int t, int par, bool tail, f32x4* accC, f32x4* accN,
                    bf16x8& cp0, bf16x8& cp1) {
        // producer backpressure (chunk edge; w0 only — the sole ring-storer)
        if constexpr (LAY < 2) {
            if (w == 0 && (t & (CP - 1)) == 0) spin_ge(consOutP, t + CP - D_RING);
        }
        // early publish (round-5 proven: drained release, cadence 16)
        if constexpr (LAY < 2) {
            if ((t & (CP - 1)) == 1 && t > 1) {
                if (tid == 0) flag_store_drain(progOut, t - 2);
            }
        }

        // h[t-1] A-frags from LDS
        const bf16x8 ha = *(const bf16x8*)(ldsb + ((par ^ 1) << 11) + rdA0);
        const bf16x8 hb = *(const bf16x8*)(ldsb + ((par ^ 1) << 11) + rdA1);

        // h-part MFMAs (critical chain)
        #pragma unroll
        for (int d = 0; d < 4; ++d) {
            accC[d] = __builtin_amdgcn_mfma_f32_16x16x32_bf16(ha, whh_f[d][0], accC[d], 0, 0, 0);
            accC[d] = __builtin_amdgcn_mfma_f32_16x16x32_bf16(hb, whh_f[d][1], accC[d], 0, 0, 0);
        }

        // wait for x(t+1) regs (counts in header)
        if (tail) {
            asm volatile("s_waitcnt vmcnt(0)" ::: "memory");
        } else if constexpr (LAY == 0) {
            if (w == 0) asm volatile("s_waitcnt vmcnt(2)" ::: "memory");
            else        asm volatile("s_waitcnt vmcnt(0)" ::: "memory");
        } else if constexpr (LAY == 1) {
            if (w == 0) asm volatile("s_waitcnt vmcnt(6)" ::: "memory");
            else        asm volatile("s_waitcnt vmcnt(2)" ::: "memory");
        } else {
            asm volatile("s_waitcnt vmcnt(2)" ::: "memory");
        }
        __builtin_amdgcn_sched_barrier(0);

        // x-part of t+1 into accN (off-chain; overlaps cell update)
        if (t + 1 < T_) {
            if constexpr (LAY == 0) {
                const bf16x8 xc = cvt_x6(xf0, xf1, xf2);
                #pragma unroll
                for (int d = 0; d < 4; ++d)
                    accN[d] = __builtin_amdgcn_mfma_f32_16x16x32_bf16(xc, wih_f[d][0], bias_acc[d], 0, 0, 0);
            } else {
                #pragma unroll
                for (int d = 0; d < 4; ++d) {
                    accN[d] = __builtin_amdgcn_mfma_f32_16x16x32_bf16(cp0, wih_f[d][0], bias_acc[d], 0, 0, 0);
                    accN[d] = __builtin_amdgcn_mfma_f32_16x16x32_bf16(cp1, wih_f[d][1], accN[d], 0, 0, 0);
                }
            }
        }

        // issue x loads FIRST (keeps them older than this step's stores)
        {
            const int s = (LAY > 0) ? t + 3 : t + 2;
            if (s < T_) {
                if constexpr (LAY > 0) {
                    if ((s & (CP - 1)) == 0) {
                        int tgt = s + CP - 1; if (tgt > T_ - 1) tgt = T_ - 1;
                        spin_ge(progIn, tgt);
                    }
                    const char* src = (const char*)ringIn + (s & (D_RING - 1)) * SLOT_BYTES;
                    asm volatile(
                        "global_load_dwordx4 %0, %2, off sc0 sc1\n\t"
                        "global_load_dwordx4 %1, %3, off sc0 sc1"
                        : "=v"(cp0), "=v"(cp1)
                        : "v"(src + rOffA), "v"(src + rOffB)
                        : "memory");
                } else {
                    asm volatile(
                        "global_load_dwordx2 %0, %3, off\n\t"
                        "global_load_dwordx2 %1, %4, off\n\t"
                        "global_load_dwordx2 %2, %5, off"
                        : "=v"(xf0), "=v"(xf1), "=v"(xf2)
                        : "v"(xaddr(s)), "v"(xaddr(s) + 8), "v"(xaddr(s) + 16)
                        : "memory");
                }
            }
        }

        // ring store of h[t-1] (wave 0; values live in ha/hb). Runs at t=0
        // too (slot 63 dummy; overwritten a revolution before any read).
        if constexpr (LAY < 2) {
            if (w == 0) {
                char* dst = (char*)ringOut + ((t - 1) & (D_RING - 1)) * SLOT_BYTES;
                ring_store16(dst + rOffA, ha);
                ring_store16(dst + rOffB, hb);
            }
        }

        // cell update (lane-local: rows 4kq+r at column hdim)
        float h[4];
        h[0] = cell_one<0>(accC, c[0]);
        h[1] = cell_one<1>(accC, c[1]);
        h[2] = cell_one<2>(accC, c[2]);
        h[3] = cell_one<3>(accC, c[3]);
        const unsigned p01 = cvtpk_bf16(h[0], h[1]);
        const unsigned p23 = cvtpk_bf16(h[2], h[3]);
        char* wbase = ldsb + (par << 11);
        *(unsigned short*)(wbase + wrA[0]) = (unsigned short)(p01 & 0xffff);
        *(unsigned short*)(wbase + wrA[1]) = (unsigned short)(p01 >> 16);
        *(unsigned short*)(wbase + wrA[2]) = (unsigned short)(p23 & 0xffff);
        *(unsigned short*)(wbase + wrA[3]) = (unsigned short)(p23 >> 16);
        if constexpr (LAY == 2) {
            if (t == T_ - 1) {
                #pragma unroll
                for (int r = 0; r < 4; ++r)
                    hlast[(g * 16 + kq * 4 + r) * 64 + hdim] = h[r];
            }
        }

        lds_barrier();   // h[t] visible; global ops stay in flight

        // consumption progress publish (plain store; baseline-identical)
        if constexpr (LAY > 0) {
            if (tid == 0 && (t & (CP - 1)) == CP - 1) flag_store(consInP, t);
        }
    };

    #pragma unroll 1
    for (int t = 0; t < T_ - 4; t += 2) {
        step(t,     0, false, accA, accB, curA0, curA1);
        step(t + 1, 1, false, accB, accA, curB0, curB1);
    }
    // tail: last 4 steps with full drains (load issue has stopped; counted
    // waits would under-wait)
    step(T_ - 4, 0, true, accA, accB, curA0, curA1);
    step(T_ - 3, 1, true, accB, accA, curB0, curB1);
    step(T_ - 2, 0, true, accA, accB, curA0, curA1);
    step(T_ - 1, 1, true, accB, accA, curB0, curB1);

    // ---- epilogue: publish h[T-1] + tail chunk (drained release) ----
    if constexpr (LAY < 2) {
        if (w == 0) {
            const int par = (T_ - 1) & 1;
            const bf16x8 ha = *(const bf16x8*)(ldsb + (par << 11) + rdA0);
            const bf16x8 hb = *(const bf16x8*)(ldsb + (par << 11) + rdA1);
            char* dst = (char*)ringOut + ((T_ - 1) & (D_RING - 1)) * SLOT_BYTES;
            ring_store16(dst + rOffA, ha);
            ring_store16(dst + rOffB, hb);
        }
        lds_barrier();
        if (tid == 0) flag_store_drain(progOut, T_ - 1);
    }
}

__global__ __launch_bounds__(256, 1)
void lstm_pipe(const float* __restrict__ xraw,
               const unsigned short* __restrict__ wih0p,
               const unsigned short* __restrict__ wih1,
               const unsigned short* __restrict__ wih2,
               const unsigned short* __restrict__ whh0,
               const unsigned short* __restrict__ whh1,
               const unsigned short* __restrict__ whh2,
               const float* __restrict__ bih0, const float* __restrict__ bhh0,
               const float* __restrict__ bih1, const float* __restrict__ bhh1,
               const float* __restrict__ bih2, const float* __restrict__ bhh2,
               unsigned short* __restrict__ ring, int* __restrict__ flags,
               float* __restrict__ hlast)
{
    __shared__ unsigned short lds[2][1024];   // 4 KiB double-buffered h tile

    const int g   = blockIdx.x & 63;
    const int lay = blockIdx.x >> 6;

    const size_t GSHORTS = (size_t)D_RING * SLOT_BYTES / 2;     // per (iface,g)
    unsigned short* r0 = ring + ((size_t)0 * NG + g) * GSHORTS;
    unsigned short* r1 = ring + ((size_t)1 * NG + g) * GSHORTS;
    int* prog0 = flags + (0 * 64 + g) * 16;
    int* prog1 = flags + (1 * 64 + g) * 16;
    int* cons0 = flags + (128 + 0 * 64 + g) * 16;
    int* cons1 = flags + (128 + 1 * 64 + g) * 16;

    if (lay == 0) {
        pipe_body<0>(g, xraw, wih0p, whh0, bih0, bhh0,
                     nullptr, r0, nullptr, prog0, nullptr, cons0,
                     hlast, &lds[0][0]);
    } else if (lay == 1) {
        pipe_body<1>(g, nullptr, wih1, whh1, bih1, bhh1,
                     r0, r1, prog0, prog1, cons0, cons1,
                     hlast, &lds[0][0]);
    } else {
        pipe_body<2>(g, nullptr, wih2, whh2, bih2, bhh2,
                     r1, nullptr, prog1, nullptr, cons1, nullptr,
                     hlast, &lds[0][0]);
    }
}

// ---------------------------------------------------------------------------
// MLP head: one block per batch row. 64 -> 128 relu -> 64 relu -> 2.
// ---------------------------------------------------------------------------
__global__ __launch_bounds__(128)
void mlp_head_kernel(const float* __restrict__ hlast,
                     const float* __restrict__ fc1_w, const float* __restrict__ fc1_b,
                     const float* __restrict__ fc3_w, const float* __restrict__ fc3_b,
                     const float* __restrict__ fc2_w, const float* __restrict__ fc2_b,
                     float* __restrict__ outp)
{
    __shared__ float s_h[H_];
    __shared__ float s_z1[128];
    __shared__ float s_z3[64];
    const int b = blockIdx.x, tid = threadIdx.x;

    if (tid < H_) s_h[tid] = hlast[b * H_ + tid];
    __syncthreads();

    {
        float acc = fc1_b[tid];
        #pragma unroll
        for (int k = 0; k < H_; ++k) acc += fc1_w[tid * H_ + k] * s_h[k];
        s_z1[tid] = fmaxf(acc, 0.0f);
    }
    __syncthreads();

    if (tid < 64) {
        float acc = fc3_b[tid];
        #pragma unroll
        for (int k = 0; k < 128; ++k) acc += fc3_w[tid * 128 + k] * s_z1[k];
        s_z3[tid] = fmaxf(acc, 0.0f);
    }
    __syncthreads();

    if (tid < 2) {
        float acc = fc2_b[tid];
        #pragma unroll
        for (int k = 0; k < 64; ++k) acc += fc2_w[tid * 64 + k] * s_z3[k];
        outp[b * 2 + tid] = acc;
    }
}

} // namespace

extern "C" void kernel_launch(void* const* d_in, const int* in_sizes, int n_in,
                              void* d_out, int out_size, void* d_ws, size_t ws_size,
                              hipStream_t stream) {
    (void)in_sizes; (void)n_in; (void)out_size; (void)ws_size;

    const float* x     = (const float*)d_in[0];
    const float* wih0  = (const float*)d_in[1];
    const float* whh0  = (const float*)d_in[2];
    const float* bih0  = (const float*)d_in[3];
    const float* bhh0  = (const float*)d_in[4];
    const float* wih1  = (const float*)d_in[5];
    const float* whh1  = (const float*)d_in[6];
    const float* bih1  = (const float*)d_in[7];
    const float* bhh1  = (const float*)d_in[8];
    const float* wih2  = (const float*)d_in[9];
    const float* whh2  = (const float*)d_in[10];
    const float* bih2  = (const float*)d_in[11];
    const float* bhh2  = (const float*)d_in[12];
    const float* fc1_w = (const float*)d_in[13];
    const float* fc1_b = (const float*)d_in[14];
    const float* fc3_w = (const float*)d_in[15];
    const float* fc3_b = (const float*)d_in[16];
    const float* fc2_w = (const float*)d_in[17];
    const float* fc2_b = (const float*)d_in[18];
    float* out = (float*)d_out;

    // ---- workspace layout (xPk eliminated) ----
    char* base = (char*)d_ws;
    const size_t RING_B = (size_t)2 * NG * D_RING * SLOT_BYTES;      // 16 MiB
    const size_t FLAG_B = 4096 * sizeof(int);                        // 16 KiB
    unsigned short* ring  = (unsigned short*)(base);
    int*            flags = (int*)(base + RING_B);
    float*          hlast = (float*)(base + RING_B + FLAG_B);
    char* wp = base + RING_B + FLAG_B + (size_t)B_ * H_ * 4;
    unsigned short* whh_b[3];
    for (int i = 0; i < 3; ++i) { whh_b[i] = (unsigned short*)wp; wp += 256 * 64 * 2; }
    unsigned short* wih_b1 = (unsigned short*)wp; wp += 256 * 64 * 2;
    unsigned short* wih_b2 = (unsigned short*)wp; wp += 256 * 64 * 2;
    unsigned short* wih0p  = (unsigned short*)wp; wp += 256 * 8 * 2;

    // ---- single fused setup launch (flags + all weight conversions) ----
    setup_all<<<344, 256, 0, stream>>>(whh0, whh1, whh2, wih1, wih2, wih0,
                                       whh_b[0], whh_b[1], whh_b[2],
                                       wih_b1, wih_b2, wih0p, flags);

    // ---- pipelined LSTM stack: 192 blocks (64 groups x 3 layers) ----
    lstm_pipe<<<192, 256, 0, stream>>>(x, wih0p, wih_b1, wih_b2,
                                       whh_b[0], whh_b[1], whh_b[2],
                                       bih0, bhh0, bih1, bhh1, bih2, bhh2,
                                       ring, flags, hlast);

    // ---- MLP head ----
    mlp_head_kernel<<<B_, 128, 0, stream>>>(hlast, fc1_w, fc1_b, fc3_w, fc3_b,
                                            fc2_w, fc2_b, out);
}